// Round 3
// baseline (20.383 us; speedup 1.0000x reference)
//
#include <hip/hip_runtime.h>
#include <hip/hip_bf16.h>
#include <math.h>

#define DD 64  // feature dim

typedef __bf16 bf16x8 __attribute__((ext_vector_type(8)));
typedef float f32x4 __attribute__((ext_vector_type(4)));

__device__ inline bf16x8 cvt8(const float4 a, const float4 b) {
  bf16x8 r;
  r[0] = (__bf16)a.x; r[1] = (__bf16)a.y; r[2] = (__bf16)a.z; r[3] = (__bf16)a.w;
  r[4] = (__bf16)b.x; r[5] = (__bf16)b.y; r[6] = (__bf16)b.z; r[7] = (__bf16)b.w;
  return r;
}

// Fused CDist: out[i][j] = sqrt(max(||xb_i||^2 + ||yb_j||^2 - 2 xb_i.yb_j, 0))
// One 64x64 output tile per 256-thread block (4 waves, 2x2; each wave 32x32).
// Fragments load directly from global fp32 and convert to bf16 in registers;
// norms are computed cooperatively into 512 B of LDS with the SAME bf16
// rounding, so d^2 >= 0 up to MFMA rounding (clamped).
__global__ __launch_bounds__(256) void cdist_fused(
    const float* __restrict__ x, const float* __restrict__ y,
    float* __restrict__ out, int N, int M) {
  const int tid  = threadIdx.x;
  const int lane = tid & 63;
  const int wid  = tid >> 6;                 // 0..3
  const int wr = wid >> 1, wc = wid & 1;     // 2x2 wave grid
  const int bi = blockIdx.y * 64;            // block's x-row base
  const int bj = blockIdx.x * 64;            // block's y-row base

  __shared__ float snx[64], sny[64];

  // --- cooperative bf16-rounded row norms: 128 rows, 2 threads per row ---
  {
    const int rid  = tid >> 1;               // 0..127
    const int half = tid & 1;                // 32 elems each
    const float* __restrict__ src =
        (rid < 64) ? &x[(size_t)(bi + rid) * DD]
                   : &y[(size_t)(bj + rid - 64) * DD];
    float s = 0.f;
    #pragma unroll
    for (int c = 0; c < 8; ++c) {
      const float4 v = *reinterpret_cast<const float4*>(&src[half * 32 + c * 4]);
      float t;
      t = (float)(__bf16)v.x; s = fmaf(t, t, s);
      t = (float)(__bf16)v.y; s = fmaf(t, t, s);
      t = (float)(__bf16)v.z; s = fmaf(t, t, s);
      t = (float)(__bf16)v.w; s = fmaf(t, t, s);
    }
    s += __shfl_down(s, 1, 64);              // pair-combine (lanes 2k,2k+1)
    if (half == 0) {
      if (rid < 64) snx[rid] = s;
      else          sny[rid - 64] = s;
    }
  }

  // --- fragment loads: fp32 global -> bf16 registers ---
  // A/B layout for mfma_f32_16x16x32_bf16: lane l holds 8 contiguous k-elems
  // of row (l&15) at k-offset (l>>4)*8. (Verified by round-2 pass.)
  const int lrow = lane & 15;
  const int kgrp = lane >> 4;
  const int i0 = bi + wr * 32;
  const int j0 = bj + wc * 32;

  bf16x8 a[2][2], b[2][2];
  #pragma unroll
  for (int m = 0; m < 2; ++m) {
    #pragma unroll
    for (int ks = 0; ks < 2; ++ks) {
      const float* px = &x[(size_t)(i0 + m * 16 + lrow) * DD + ks * 32 + kgrp * 8];
      const float* py = &y[(size_t)(j0 + m * 16 + lrow) * DD + ks * 32 + kgrp * 8];
      a[m][ks] = cvt8(*reinterpret_cast<const float4*>(px),
                      *reinterpret_cast<const float4*>(px + 4));
      b[m][ks] = cvt8(*reinterpret_cast<const float4*>(py),
                      *reinterpret_cast<const float4*>(py + 4));
    }
  }

  f32x4 acc[2][2] = {};
  #pragma unroll
  for (int ks = 0; ks < 2; ++ks)
    #pragma unroll
    for (int m = 0; m < 2; ++m)
      #pragma unroll
      for (int n = 0; n < 2; ++n)
        acc[m][n] = __builtin_amdgcn_mfma_f32_16x16x32_bf16(
            a[m][ks], b[n][ks], acc[m][n], 0, 0, 0);

  __syncthreads();  // norms visible

  // --- epilogue: C/D layout col = lane&15, row = (lane>>4)*4 + reg ---
  const int rbase = kgrp * 4;
  float nyv[2];
  nyv[0] = sny[wc * 32 + lrow];
  nyv[1] = sny[wc * 32 + 16 + lrow];

  #pragma unroll
  for (int m = 0; m < 2; ++m) {
    #pragma unroll
    for (int r = 0; r < 4; ++r) {
      const int lr  = wr * 32 + m * 16 + rbase + r;   // row within block
      const float nxv = snx[lr];
      float* __restrict__ orow = &out[(size_t)(bi + lr) * M + bj + wc * 32];
      #pragma unroll
      for (int n = 0; n < 2; ++n) {
        const float d2 = fmaf(-2.0f, acc[m][n][r], nxv + nyv[n]);
        orow[n * 16 + lrow] = sqrtf(fmaxf(d2, 0.0f));
      }
    }
  }
}

extern "C" void kernel_launch(void* const* d_in, const int* in_sizes, int n_in,
                              void* d_out, int out_size, void* d_ws, size_t ws_size,
                              hipStream_t stream) {
  const float* x = (const float*)d_in[0];
  const float* y = (const float*)d_in[1];
  float* out = (float*)d_out;
  const int N = in_sizes[0] / DD;  // 2048
  const int M = in_sizes[1] / DD;  // 2048

  cdist_fused<<<dim3(M / 64, N / 64), dim3(256), 0, stream>>>(x, y, out, N, M);
}

// Round 4
// 17.330 us; speedup vs baseline: 1.1762x; 1.1762x over previous
//
#include <hip/hip_runtime.h>
#include <hip/hip_bf16.h>
#include <math.h>

#define DD 64  // feature dim

typedef __bf16 bf16x8 __attribute__((ext_vector_type(8)));
typedef float f32x4 __attribute__((ext_vector_type(4)));

// Convert 8 fp32 -> bf16 fragment, accumulating sum of squares of the
// bf16-ROUNDED values into s (so d^2 = nx+ny-2dot = ||xb-yb||^2 >= 0).
__device__ inline bf16x8 cvt8n(const float4 a, const float4 b, float& s) {
  bf16x8 r;
  float t;
  r[0] = (__bf16)a.x; t = (float)r[0]; s = fmaf(t, t, s);
  r[1] = (__bf16)a.y; t = (float)r[1]; s = fmaf(t, t, s);
  r[2] = (__bf16)a.z; t = (float)r[2]; s = fmaf(t, t, s);
  r[3] = (__bf16)a.w; t = (float)r[3]; s = fmaf(t, t, s);
  r[4] = (__bf16)b.x; t = (float)r[4]; s = fmaf(t, t, s);
  r[5] = (__bf16)b.y; t = (float)r[5]; s = fmaf(t, t, s);
  r[6] = (__bf16)b.z; t = (float)r[6]; s = fmaf(t, t, s);
  r[7] = (__bf16)b.w; t = (float)r[7]; s = fmaf(t, t, s);
  return r;
}

// Fully fused CDist, no LDS, no __syncthreads, single phase:
//   out[i][j] = sqrt(max(||xb_i||^2 + ||yb_j||^2 - 2 xb_i.yb_j, 0))
// Block = 4 independent waves (2x2), each wave owns a 32x32 output tile.
// Row norms fall out of the fragment conversion (butterfly over k-group
// lanes). MFMA operands are SWAPPED (y as A, x as B) so the C/D layout is
// row->j, col->i: each lane's 4 acc regs are 4 consecutive j -> float4 store.
__global__ __launch_bounds__(256) void cdist_fused(
    const float* __restrict__ x, const float* __restrict__ y,
    float* __restrict__ out, int N, int M) {
  const int lane = threadIdx.x & 63;
  const int wid  = threadIdx.x >> 6;         // 0..3
  const int wr = wid >> 1, wc = wid & 1;     // 2x2 wave grid
  const int i0 = blockIdx.y * 64 + wr * 32;  // wave's x-row base
  const int j0 = blockIdx.x * 64 + wc * 32;  // wave's y-row base
  const int lrow = lane & 15;
  const int kgrp = lane >> 4;

  // Fragment loads (fp32 global -> bf16 regs) + partial norms.
  // A/B layout: lane l holds 8 contiguous k-elems of row (l&15), k-offset
  // (l>>4)*8 (+32 per k-step). Verified in rounds 2-3.
  bf16x8 a[2][2], b[2][2];
  float sa[2] = {0.f, 0.f}, sb[2] = {0.f, 0.f};
  #pragma unroll
  for (int m = 0; m < 2; ++m) {
    #pragma unroll
    for (int ks = 0; ks < 2; ++ks) {
      const float* px = &x[(size_t)(i0 + m * 16 + lrow) * DD + ks * 32 + kgrp * 8];
      a[m][ks] = cvt8n(*reinterpret_cast<const float4*>(px),
                       *reinterpret_cast<const float4*>(px + 4), sa[m]);
      const float* py = &y[(size_t)(j0 + m * 16 + lrow) * DD + ks * 32 + kgrp * 8];
      b[m][ks] = cvt8n(*reinterpret_cast<const float4*>(py),
                       *reinterpret_cast<const float4*>(py + 4), sb[m]);
    }
  }

  // Butterfly over the kgrp bits: every lane gets the full norm of the row
  // (base + frag*16 + lrow) it loaded.
  #pragma unroll
  for (int m = 0; m < 2; ++m) {
    sa[m] += __shfl_xor(sa[m], 16, 64);
    sa[m] += __shfl_xor(sa[m], 32, 64);
    sb[m] += __shfl_xor(sb[m], 16, 64);
    sb[m] += __shfl_xor(sb[m], 32, 64);
  }

  // Swapped-operand MFMA: D[row -> j][col -> i].
  f32x4 acc[2][2] = {};  // acc[n][m]
  #pragma unroll
  for (int ks = 0; ks < 2; ++ks)
    #pragma unroll
    for (int n = 0; n < 2; ++n)
      #pragma unroll
      for (int m = 0; m < 2; ++m)
        acc[n][m] = __builtin_amdgcn_mfma_f32_16x16x32_bf16(
            b[n][ks], a[m][ks], acc[n][m], 0, 0, 0);

  // Epilogue: lane's output element (for frag m,n, reg r):
  //   i = i0 + m*16 + lrow   (x-norm = own sa[m])
  //   j = j0 + n*16 + kgrp*4 + r  (y-norm fetched from lane kgrp*4+r)
  #pragma unroll
  for (int n = 0; n < 2; ++n) {
    float nyv[4];
    #pragma unroll
    for (int r = 0; r < 4; ++r) nyv[r] = __shfl(sb[n], kgrp * 4 + r, 64);
    #pragma unroll
    for (int m = 0; m < 2; ++m) {
      float4 res;
      float d2;
      d2 = fmaf(-2.0f, acc[n][m][0], sa[m] + nyv[0]); res.x = sqrtf(fmaxf(d2, 0.f));
      d2 = fmaf(-2.0f, acc[n][m][1], sa[m] + nyv[1]); res.y = sqrtf(fmaxf(d2, 0.f));
      d2 = fmaf(-2.0f, acc[n][m][2], sa[m] + nyv[2]); res.z = sqrtf(fmaxf(d2, 0.f));
      d2 = fmaf(-2.0f, acc[n][m][3], sa[m] + nyv[3]); res.w = sqrtf(fmaxf(d2, 0.f));
      *reinterpret_cast<float4*>(
          &out[(size_t)(i0 + m * 16 + lrow) * M + j0 + n * 16 + kgrp * 4]) = res;
    }
  }
}

extern "C" void kernel_launch(void* const* d_in, const int* in_sizes, int n_in,
                              void* d_out, int out_size, void* d_ws, size_t ws_size,
                              hipStream_t stream) {
  const float* x = (const float*)d_in[0];
  const float* y = (const float*)d_in[1];
  float* out = (float*)d_out;
  const int N = in_sizes[0] / DD;  // 2048
  const int M = in_sizes[1] / DD;  // 2048

  cdist_fused<<<dim3(M / 64, N / 64), dim3(256), 0, stream>>>(x, y, out, N, M);
}